// Round 7
// baseline (642.541 us; speedup 1.0000x reference)
//
#include <hip/hip_runtime.h>
#include <cstdint>
#include <cstddef>

#define BSZ 16
#define TLEN 2048
#define CDIM 1024
#define OUTDIM 512
#define MAXF 512

typedef _Float16 f16x8 __attribute__((ext_vector_type(8)));
typedef _Float16 f16x4 __attribute__((ext_vector_type(4)));
typedef float f32x16 __attribute__((ext_vector_type(16)));

__device__ __forceinline__ void gl_lds16(const void* g, void* l) {
    __builtin_amdgcn_global_load_lds(
        (const __attribute__((address_space(1))) void*)g,
        (__attribute__((address_space(3))) void*)l, 16, 0, 0);
}

// exact 2-term fp16 split: a = h0 + h1 * 2^-11  (h1 pre-scaled by 2^11)
struct h2pair { _Float16 h0, h1; };
__device__ __forceinline__ h2pair split2(float a) {
    h2pair o;
    o.h0 = (_Float16)a;
    float r = a - (float)o.h0;       // exact (Sterbenz)
    o.h1 = (_Float16)(r * 2048.0f);
    return o;
}

// ============================================================================
// k0_prep: FUSED (was: memset(g) + k0a + k0c = 3 dispatches).
//  bx <  256: Wd -> tiled fp16 planes (dut = bx>>5, ktl = bx&31; 128 active thr)
//  bx >= 256: Wo -> row-major fp16 planes + zero g[32768]
// ============================================================================
__global__ __launch_bounds__(256) void k0_prep(
    const float* __restrict__ Wd, _Float16* __restrict__ B0,
    _Float16* __restrict__ B1, const float* __restrict__ Wo,
    _Float16* __restrict__ W0, _Float16* __restrict__ W1,
    float* __restrict__ g)
{
    const int bx = blockIdx.x;
    const int tid = threadIdx.x;
    if (bx < 256) {
        if (tid < 128) {
            const int dut = bx >> 5;    // 8
            const int ktl = bx & 31;    // 32
            const int r = tid;          // 128
            const float* src = Wd + (size_t)(dut * 128 + r) * CDIM + ktl * 32;
            float v[32];
#pragma unroll
            for (int j = 0; j < 8; j++)
                *(float4*)&v[j * 4] = *(const float4*)(src + j * 4);
            const size_t tb = (size_t)(dut * 32 + ktl) * 4096;
#pragma unroll
            for (int c = 0; c < 4; c++) {
                f16x8 h0, h1;
#pragma unroll
                for (int j = 0; j < 8; j++) {
                    h2pair s = split2(v[c * 8 + j]);
                    h0[j] = s.h0;
                    h1[j] = s.h1;
                }
                *(f16x8*)&B0[tb + (c * 128 + r) * 8] = h0;
                *(f16x8*)&B1[tb + (c * 128 + r) * 8] = h1;
            }
        }
    } else {
        const int gi = (bx - 256) * 256 + tid;      // 0..131071
        const int i = gi * 4;
        float4 v = *(const float4*)(Wo + i);
        f16x4 h0, h1;
        h2pair s0 = split2(v.x); h0[0] = s0.h0; h1[0] = s0.h1;
        h2pair s1 = split2(v.y); h0[1] = s1.h0; h1[1] = s1.h1;
        h2pair s2 = split2(v.z); h0[2] = s2.h0; h1[2] = s2.h1;
        h2pair s3 = split2(v.w); h0[3] = s3.h0; h1[3] = s3.h1;
        *(f16x4*)&W0[i] = h0;
        *(f16x4*)&W1[i] = h1;
        if (gi < BSZ * TLEN) g[gi] = 0.f;
    }
}

// ============================================================================
// k1: g[row] = sum_du Wp[du]*relu(enc[row,:].Wd[du,:] + bd[du])
// R4/R6's proven kernel, verbatim (260 us, MfmaUtil 36, occ 43%). Frozen.
// ============================================================================
__global__ __launch_bounds__(512, 4) void k1_weight_gemm(
    const float* __restrict__ enc, const _Float16* __restrict__ BT0,
    const _Float16* __restrict__ BT1, const float* __restrict__ bd,
    const float* __restrict__ Wp, float* __restrict__ g)
{
    // 2 buffers x (A0|A1|B0|B1 regions of 4096 halves) = 32768 halves = 64KB
    __shared__ __align__(16) _Float16 lds[32768];

    const int tid = threadIdx.x;
    const int lane = tid & 63;
    const int wv = tid >> 6;        // 0..7
    const int l5 = lane & 31;
    const int hi = lane >> 5;
    const int mtb = (wv & 1) * 64;  // M half
    const int ntb = (wv >> 1) * 32; // N quarter (32 du)

    // XCD-aware decode: xcd = bx%8; each xcd handles 32 row-groups x 8 du
    const int bx = blockIdx.x;
    const int xcd = bx & 7;
    const int j = bx >> 3;
    const int rg = xcd * 32 + (j >> 3);
    const int dug = j & 7;
    const long row0 = (long)rg * 128;
    const int du0 = dug * 128;

    // A staging: row sr = (wv>>2)*64 + lane, k-octet sq = wv&3 (wave-uniform)
    const int sgrp = wv >> 2;       // 0..1
    const int sq = wv & 3;          // 0..3
    const int sr = sgrp * 64 + lane;
    const float* aptr = enc + (row0 + sr) * (long)CDIM + sq * 8;
    const int aw0 = (sq * 128 + sr) * 8;   // A0 LDS write offset (halves)

    // B staging: wave stages quarter sq of plane sgrp (2 x gl_lds16 of 1KB)
    const _Float16* bsrc = (sgrp ? BT1 : BT0)
        + (size_t)(dug * 32) * 4096 + sq * 1024 + lane * 8;
    const int bldofs = 8192 + sgrp * 4096 + sq * 1024;

    f32x16 acc[2], accc[2];
#pragma unroll
    for (int mt = 0; mt < 2; mt++)
#pragma unroll
        for (int r = 0; r < 16; r++) { acc[mt][r] = 0.f; accc[mt][r] = 0.f; }

    float fa[8];

    // ---- prologue: stage tile 0 into buf0, prefetch fa(tile 1) ----
    *(float4*)&fa[0] = *(const float4*)(aptr + 0);
    *(float4*)&fa[4] = *(const float4*)(aptr + 4);
    gl_lds16(bsrc, &lds[bldofs]);
    gl_lds16(bsrc + 512, &lds[bldofs + 512]);
    asm volatile("" ::: "memory");
    {
        f16x8 h0, h1;
#pragma unroll
        for (int jj = 0; jj < 8; jj++) {
            h2pair s = split2(fa[jj]);
            h0[jj] = s.h0;
            h1[jj] = s.h1;
        }
        *(f16x8*)&lds[aw0] = h0;
        *(f16x8*)&lds[4096 + aw0] = h1;
    }
    *(float4*)&fa[0] = *(const float4*)(aptr + 32);
    *(float4*)&fa[4] = *(const float4*)(aptr + 36);
    asm volatile("s_waitcnt vmcnt(2) lgkmcnt(0)" ::: "memory");
    __builtin_amdgcn_s_barrier();

    for (int kt = 0; kt < 32; ++kt) {
        const int cur = (kt & 1) * 16384;
        const int nxt = cur ^ 16384;
        __builtin_amdgcn_sched_barrier(0);

        if (kt < 31) {
            // B(kt+1) DMA into nxt — in flight through this tile's MFMA
            const _Float16* bs = bsrc + (size_t)(kt + 1) * 4096;
            gl_lds16(bs, &lds[nxt + bldofs]);
            gl_lds16(bs + 512, &lds[nxt + bldofs + 512]);
            asm volatile("" ::: "memory");
            // split fa (= tile kt+1) into nxt A planes
            f16x8 h0, h1;
#pragma unroll
            for (int jj = 0; jj < 8; jj++) {
                h2pair s = split2(fa[jj]);
                h0[jj] = s.h0;
                h1[jj] = s.h1;
            }
            *(f16x8*)&lds[nxt + aw0] = h0;
            *(f16x8*)&lds[nxt + 4096 + aw0] = h1;
            if (kt < 30) {
                *(float4*)&fa[0] = *(const float4*)(aptr + (kt + 2) * 32);
                *(float4*)&fa[4] = *(const float4*)(aptr + (kt + 2) * 32 + 4);
            }
            asm volatile("" ::: "memory");
        }

        // ---- compute on cur: 2 phases (cq = p*2 + hi), 6 MFMA each ----
#pragma unroll
        for (int p = 0; p < 2; p++) {
            const int cq = p * 2 + hi;
            f16x8 A0[2], A1[2], B0, B1;
#pragma unroll
            for (int mt = 0; mt < 2; mt++) {
                const int ro = (cq * 128 + mtb + mt * 32 + l5) * 8;
                A0[mt] = *(const f16x8*)&lds[cur + ro];
                A1[mt] = *(const f16x8*)&lds[cur + 4096 + ro];
            }
            {
                const int ro = (cq * 128 + ntb + l5) * 8;
                B0 = *(const f16x8*)&lds[cur + 8192 + ro];
                B1 = *(const f16x8*)&lds[cur + 12288 + ro];
            }
            __builtin_amdgcn_s_setprio(1);
#pragma unroll
            for (int mt = 0; mt < 2; mt++) {
                acc[mt] = __builtin_amdgcn_mfma_f32_32x32x16_f16(
                    A0[mt], B0, acc[mt], 0, 0, 0);
                accc[mt] = __builtin_amdgcn_mfma_f32_32x32x16_f16(
                    A0[mt], B1, accc[mt], 0, 0, 0);
                accc[mt] = __builtin_amdgcn_mfma_f32_32x32x16_f16(
                    A1[mt], B0, accc[mt], 0, 0, 0);
            }
            __builtin_amdgcn_s_setprio(0);
        }

        // counted drain: B DMAs complete; fa prefetch stays in flight
        if (kt < 31) {
            if (kt < 30)
                asm volatile("s_waitcnt vmcnt(2) lgkmcnt(0)" ::: "memory");
            else
                asm volatile("s_waitcnt vmcnt(0) lgkmcnt(0)" ::: "memory");
            __builtin_amdgcn_s_barrier();
        }
    }

    // epilogue: h = relu(acc_total + bd[n]); g += Wp[n]*h reduced over n
    const float bdv = bd[du0 + ntb + l5];
    const float wpv = Wp[du0 + ntb + l5];
    float out = 0.f;
#pragma unroll
    for (int mt = 0; mt < 2; mt++)
#pragma unroll
        for (int r = 0; r < 16; r++) {
            float h = acc[mt][r] + 4.8828125e-4f * accc[mt][r] + bdv;
            h = h > 0.f ? h : 0.f;
            float s = wpv * h;
            s += __shfl_xor(s, 1);
            s += __shfl_xor(s, 2);
            s += __shfl_xor(s, 4);
            s += __shfl_xor(s, 8);
            s += __shfl_xor(s, 16);
            if (l5 == mt * 16 + r) out = s;
        }
    const int mt_sel = l5 >> 4;
    const int r_sel = l5 & 15;
    const int row = mtb + mt_sel * 32 + (r_sel & 3) + 8 * (r_sel >> 2) + 4 * hi;
    atomicAdd(&g[row0 + row], out);
}

// ============================================================================
// k2: per-batch sigmoid + masked sum + scale + sequential scan.
// NOW also writes the FULL out_mask/out_dur rows (zeros beyond nf), so the
// d_out memset can be dropped.
// ============================================================================
__global__ __launch_bounds__(256) void k2_scan(
    const float* __restrict__ g, const int* __restrict__ in_len,
    const int* __restrict__ tgt_len, const float* __restrict__ bp,
    float* __restrict__ c_a, float* __restrict__ c_b,
    int* __restrict__ fire_t, int* __restrict__ n_fired,
    float* __restrict__ out_mask, float* __restrict__ out_dur,
    float* __restrict__ out_qty)
{
    __shared__ float w[TLEN];
    __shared__ float ca[TLEN];
    __shared__ float cb[TLEN];
    __shared__ int fires[MAXF];
    __shared__ float ssum[256];
    __shared__ float s_scale;
    __shared__ int s_nf;

    const int b = blockIdx.x;
    const int tid = threadIdx.x;
    const int len = in_len[b];
    const float bpv = bp[0];

    float local = 0.f;
    for (int t = tid; t < TLEN; t += 256) {
        float gv = g[b * TLEN + t] + bpv;
        float s = 1.f / (1.f + expf(-gv));
        float ow = (t < len) ? s : 0.f;
        w[t] = ow;
        local += ow;
    }
    ssum[tid] = local;
    __syncthreads();
    for (int st = 128; st > 0; st >>= 1) {
        if (tid < st) ssum[tid] += ssum[tid + st];
        __syncthreads();
    }
    if (tid == 0) {
        float org_sum = ssum[0];
        out_qty[b] = org_sum;
        s_scale = (float)tgt_len[b] / (org_sum + 1e-8f);
    }
    __syncthreads();
    float scale = s_scale;
    for (int t = tid; t < TLEN; t += 256) w[t] *= scale;
    __syncthreads();

    if (tid == 0) {
        float accw = 0.f;
        int k = 0;
        int t = 0;
        for (; t + 8 <= len; t += 8) {
            float4 wa = *(const float4*)&w[t];
            float4 wb4 = *(const float4*)&w[t + 4];
            float wv8[8] = {wa.x, wa.y, wa.z, wa.w, wb4.x, wb4.y, wb4.z, wb4.w};
#pragma unroll
            for (int u = 0; u < 8; u++) {
                float wt = wv8[u];
                float aw = accw + wt;
                bool f = (aw >= 1.0f);
                float rem = 1.0f - accw;          // exact reference order
                float fb = wt - rem;
                ca[t + u] = f ? rem : wt;
                cb[t + u] = f ? fb : 0.f;
                fires[k & (MAXF - 1)] = t + u;    // commits on fire
                k += f ? 1 : 0;
                accw = f ? fb : aw;
            }
        }
        for (; t < len; t++) {
            float wt = w[t];
            float aw = accw + wt;
            bool f = (aw >= 1.0f);
            float rem = 1.0f - accw;
            float fb = wt - rem;
            ca[t] = f ? rem : wt;
            cb[t] = f ? fb : 0.f;
            fires[k & (MAXF - 1)] = t;
            k += f ? 1 : 0;
            accw = f ? fb : aw;
        }
        s_nf = (k < MAXF) ? k : MAXF;
        n_fired[b] = s_nf;
    }
    __syncthreads();

    for (int t = tid; t < len; t += 256) {
        c_a[b * TLEN + t] = ca[t];
        c_b[b * TLEN + t] = cb[t];
    }
    const int nf = s_nf;
    for (int jj = tid; jj < TLEN; jj += 256) {
        if (jj < nf) {
            int tj = fires[jj];
            fire_t[b * MAXF + jj] = tj;
            out_mask[b * TLEN + jj] = 1.0f;
            int prev = (jj == 0) ? 0 : fires[jj - 1];
            out_dur[b * TLEN + jj] = (float)(tj - prev);
        } else {
            out_mask[b * TLEN + jj] = 0.0f;
            out_dur[b * TLEN + jj] = 0.0f;
        }
    }
    if (tid == 0 && nf == 0) out_mask[b * TLEN] = 1.0f;
}

// ============================================================================
// k3a: compact fired frames (segmented weighted sums, ascending t), writing
// fp16 split planes row-major [b][frame][k]; rows >= n_fired zero-filled.
// ============================================================================
__global__ __launch_bounds__(256) void k3a_compact(
    const float* __restrict__ enc, const float* __restrict__ c_a,
    const float* __restrict__ c_b, const int* __restrict__ fire_t,
    const int* __restrict__ n_fired, _Float16* __restrict__ C0,
    _Float16* __restrict__ C1)
{
    const int b = blockIdx.y;
    const int k = blockIdx.x;
    const int tid = threadIdx.x;
    _Float16* d0 = C0 + ((size_t)b * MAXF + k) * CDIM + tid * 4;
    _Float16* d1 = C1 + ((size_t)b * MAXF + k) * CDIM + tid * 4;
    if (k >= n_fired[b]) {
        f16x4 z = {(_Float16)0.f, (_Float16)0.f, (_Float16)0.f, (_Float16)0.f};
        *(f16x4*)d0 = z;
        *(f16x4*)d1 = z;
        return;
    }
    const int tend = fire_t[b * MAXF + k];
    const int tprev = (k == 0) ? -1 : fire_t[b * MAXF + k - 1];
    float ax = 0.f, ay = 0.f, az = 0.f, aw = 0.f;
    const int tstart = (tprev < 0) ? 0 : tprev;
    for (int t = tstart; t <= tend; t++) {
        float coef = (t == tprev) ? c_b[b * TLEN + t] : c_a[b * TLEN + t];
        const float4 e = *(const float4*)(enc + ((size_t)b * TLEN + t) * CDIM + tid * 4);
        ax += coef * e.x;
        ay += coef * e.y;
        az += coef * e.z;
        aw += coef * e.w;
    }
    f16x4 h0, h1;
    h2pair s0 = split2(ax); h0[0] = s0.h0; h1[0] = s0.h1;
    h2pair s1 = split2(ay); h0[1] = s1.h0; h1[1] = s1.h1;
    h2pair s2 = split2(az); h0[2] = s2.h0; h1[2] = s2.h1;
    h2pair s3 = split2(aw); h0[3] = s3.h0; h1[3] = s3.h1;
    *(f16x4*)d0 = h0;
    *(f16x4*)d1 = h1;
}

// ============================================================================
// k3b: cif_outputs[b,j,o] = compact[b,j,:].Wo[o,:] — fp16-3 MFMA.
// Grid x extended to 32 (covers all TLEN rows): blocks with j0 >= nf take a
// pure zero-write path (replaces the d_out memset for rows >= nf and the
// [MAXF, TLEN) tail); GEMM path identical to prior round.
// ============================================================================
__global__ __launch_bounds__(256) void k3b_outproj(
    const _Float16* __restrict__ C0, const _Float16* __restrict__ C1,
    const _Float16* __restrict__ W0, const _Float16* __restrict__ W1,
    const int* __restrict__ n_fired, float* __restrict__ out0)
{
    // A0[0,2048) A1[2048,4096) B0[4096,8192) B1[8192,12288) halves = 24 KB
    __shared__ __align__(16) _Float16 lds[12288];

    const int b = blockIdx.z;
    const int nf = n_fired[b];
    const int j0 = blockIdx.x * 64;
    const int o0 = blockIdx.y * 128;
    const int tid = threadIdx.x;

    if (j0 >= nf) {
        // zero-write 64 rows x 128 cols (coalesced: 32 thr/row x float4)
        const float4 z4 = {0.f, 0.f, 0.f, 0.f};
#pragma unroll
        for (int q = 0; q < 8; q++) {
            const int idx = q * 256 + tid;     // 0..2047
            const int m = idx >> 5;            // 0..63
            const int c4 = idx & 31;           // 0..31
            *(float4*)&out0[((size_t)b * TLEN + j0 + m) * OUTDIM + o0 + c4 * 4] = z4;
        }
        return;
    }

    const int lane = tid & 63;
    const int wv = tid >> 6;        // 0..3
    const int l5 = lane & 31;
    const int hi = lane >> 5;
    const int ntb = wv * 32;        // N quarter

    // B staging: 128 rows, 2 k-halves, 2 chunks
    const int sr = tid >> 1;
    const int sh = tid & 1;
    const _Float16* b0p = W0 + (size_t)(o0 + sr) * CDIM + sh * 16;
    const _Float16* b1p = W1 + (size_t)(o0 + sr) * CDIM + sh * 16;
    // A staging: 64 rows, 4 k-octets, 1 f16x8 per plane per thread
    const int ar = tid >> 2;
    const int aq = tid & 3;
    const _Float16* a0p = C0 + ((size_t)b * MAXF + j0 + ar) * CDIM + aq * 8;
    const _Float16* a1p = C1 + ((size_t)b * MAXF + j0 + ar) * CDIM + aq * 8;
    const int awofs = (aq * 64 + ar) * 8;

    f32x16 acc[2], accc[2];
#pragma unroll
    for (int mt = 0; mt < 2; mt++)
#pragma unroll
        for (int r = 0; r < 16; r++) { acc[mt][r] = 0.f; accc[mt][r] = 0.f; }

    f16x8 xa0, xa1, xb0[2], xb1[2];
    xa0 = *(const f16x8*)(a0p);
    xa1 = *(const f16x8*)(a1p);
#pragma unroll
    for (int c = 0; c < 2; c++) {
        xb0[c] = *(const f16x8*)(b0p + c * 8);
        xb1[c] = *(const f16x8*)(b1p + c * 8);
    }

    for (int kt = 0; kt < 32; ++kt) {
        __syncthreads();
        *(f16x8*)&lds[awofs] = xa0;
        *(f16x8*)&lds[2048 + awofs] = xa1;
#pragma unroll
        for (int c = 0; c < 2; c++) {
            *(f16x8*)&lds[4096 + ((sh * 2 + c) * 128 + sr) * 8] = xb0[c];
            *(f16x8*)&lds[8192 + ((sh * 2 + c) * 128 + sr) * 8] = xb1[c];
        }
        __syncthreads();
        if (kt < 31) {
            const int o = (kt + 1) * 32;
            xa0 = *(const f16x8*)(a0p + o);
            xa1 = *(const f16x8*)(a1p + o);
#pragma unroll
            for (int c = 0; c < 2; c++) {
                xb0[c] = *(const f16x8*)(b0p + o + c * 8);
                xb1[c] = *(const f16x8*)(b1p + o + c * 8);
            }
        }
#pragma unroll
        for (int ks = 0; ks < 2; ks++) {
            const int ch = ks * 2 + hi;
            f16x8 A0[2], A1[2], B0, B1;
#pragma unroll
            for (int mt = 0; mt < 2; mt++) {
                const int ro = (ch * 64 + mt * 32 + l5) * 8;
                A0[mt] = *(const f16x8*)&lds[ro];
                A1[mt] = *(const f16x8*)&lds[2048 + ro];
            }
            {
                const int ro = (ch * 128 + ntb + l5) * 8;
                B0 = *(const f16x8*)&lds[4096 + ro];
                B1 = *(const f16x8*)&lds[8192 + ro];
            }
#pragma unroll
            for (int mt = 0; mt < 2; mt++) {
                acc[mt] = __builtin_amdgcn_mfma_f32_32x32x16_f16(
                    A0[mt], B0, acc[mt], 0, 0, 0);
                accc[mt] = __builtin_amdgcn_mfma_f32_32x32x16_f16(
                    A0[mt], B1, accc[mt], 0, 0, 0);
                accc[mt] = __builtin_amdgcn_mfma_f32_32x32x16_f16(
                    A1[mt], B0, accc[mt], 0, 0, 0);
            }
        }
    }

#pragma unroll
    for (int mt = 0; mt < 2; mt++)
#pragma unroll
        for (int r = 0; r < 16; r++) {
            float val = acc[mt][r] + 4.8828125e-4f * accc[mt][r];
            int m = mt * 32 + (r & 3) + 8 * (r >> 2) + 4 * hi;
            int col = o0 + ntb + l5;
            out0[((size_t)b * TLEN + j0 + m) * OUTDIM + col] = val;
        }
}

// ============================================================================
// Host launch — 5 dispatches (was 8): prep, k1, k2, k3a, k3b. No memsets.
// ============================================================================
extern "C" void kernel_launch(void* const* d_in, const int* in_sizes, int n_in,
                              void* d_out, int out_size, void* d_ws, size_t ws_size,
                              hipStream_t stream)
{
    const float* enc = (const float*)d_in[0];
    const int* in_len = (const int*)d_in[1];
    const int* tgt_len = (const int*)d_in[2];
    const float* Wd = (const float*)d_in[3];
    const float* bd = (const float*)d_in[4];
    const float* Wp = (const float*)d_in[5];
    const float* bp = (const float*)d_in[6];
    const float* Wo = (const float*)d_in[7];

    char* ws = (char*)d_ws;
    float* g       = (float*)(ws + 0);             // 128 KB
    float* c_a     = (float*)(ws + 131072);        // 128 KB
    float* c_b     = (float*)(ws + 262144);        // 128 KB
    int* fire_t    = (int*)(ws + 393216);          // 32 KB
    int* n_fired   = (int*)(ws + 425984);          // 64 B
    _Float16* WdT0 = (_Float16*)(ws + 458752);     // 2 MB tiled
    _Float16* WdT1 = (_Float16*)(ws + 2555904);    // 2 MB
    _Float16* Wo0  = (_Float16*)(ws + 4653056);    // 1 MB row-major
    _Float16* Wo1  = (_Float16*)(ws + 5701632);    // 1 MB
    _Float16* C0   = (_Float16*)(ws + 6750208);    // 16 MB
    _Float16* C1   = (_Float16*)(ws + 23527424);   // 16 MB  (end ~40.3 MB)

    float* out0 = (float*)d_out;
    float* out_mask = out0 + (size_t)BSZ * TLEN * OUTDIM;
    float* out_dur = out_mask + (size_t)BSZ * TLEN;
    float* out_qty = out_dur + (size_t)BSZ * TLEN;

    k0_prep<<<768, 256, 0, stream>>>(Wd, WdT0, WdT1, Wo, Wo0, Wo1, g);
    k1_weight_gemm<<<2048, 512, 0, stream>>>(enc, WdT0, WdT1, bd, Wp, g);
    k2_scan<<<BSZ, 256, 0, stream>>>(g, in_len, tgt_len, bp, c_a, c_b,
                                     fire_t, n_fired, out_mask, out_dur, out_qty);
    k3a_compact<<<dim3(MAXF, BSZ), 256, 0, stream>>>(enc, c_a, c_b, fire_t,
                                                     n_fired, C0, C1);
    k3b_outproj<<<dim3(32, 4, BSZ), 256, 0, stream>>>(C0, C1, Wo0, Wo1,
                                                      n_fired, out0);
}

// Round 8
// 592.171 us; speedup vs baseline: 1.0851x; 1.0851x over previous
//
#include <hip/hip_runtime.h>
#include <cstdint>
#include <cstddef>

#define BSZ 16
#define TLEN 2048
#define CDIM 1024
#define OUTDIM 512
#define MAXF 512

typedef _Float16 f16x8 __attribute__((ext_vector_type(8)));
typedef _Float16 f16x4 __attribute__((ext_vector_type(4)));
typedef float f32x16 __attribute__((ext_vector_type(16)));

__device__ __forceinline__ void gl_lds16(const void* g, void* l) {
    __builtin_amdgcn_global_load_lds(
        (const __attribute__((address_space(1))) void*)g,
        (__attribute__((address_space(3))) void*)l, 16, 0, 0);
}

// exact 2-term fp16 split: a = h0 + h1 * 2^-11  (h1 pre-scaled by 2^11)
struct h2pair { _Float16 h0, h1; };
__device__ __forceinline__ h2pair split2(float a) {
    h2pair o;
    o.h0 = (_Float16)a;
    float r = a - (float)o.h0;       // exact (Sterbenz)
    o.h1 = (_Float16)(r * 2048.0f);
    return o;
}

// ============================================================================
// k0a: split Wd into 2 fp16 planes in k1's TILED layout:
// plane[(dut*32+ktl)*4096 + (c*128 + r)*8 + j] = Wd[dut*128+r][ktl*32+c*8+j]
// ============================================================================
__global__ __launch_bounds__(128) void k0a_split_wd(
    const float* __restrict__ Wd, _Float16* __restrict__ B0,
    _Float16* __restrict__ B1)
{
    const int dut = blockIdx.x;     // 8
    const int ktl = blockIdx.y;     // 32
    const int r = threadIdx.x;      // 128
    const float* src = Wd + (size_t)(dut * 128 + r) * CDIM + ktl * 32;
    float v[32];
#pragma unroll
    for (int j = 0; j < 8; j++) *(float4*)&v[j * 4] = *(const float4*)(src + j * 4);
    const size_t tb = (size_t)(dut * 32 + ktl) * 4096;
#pragma unroll
    for (int c = 0; c < 4; c++) {
        f16x8 h0, h1;
#pragma unroll
        for (int j = 0; j < 8; j++) {
            h2pair s = split2(v[c * 8 + j]);
            h0[j] = s.h0;
            h1[j] = s.h1;
        }
        *(f16x8*)&B0[tb + (c * 128 + r) * 8] = h0;
        *(f16x8*)&B1[tb + (c * 128 + r) * 8] = h1;
    }
}

// ============================================================================
// k0c: split Wo into 2 fp16 planes, row-major [o][k]
// ============================================================================
__global__ __launch_bounds__(256) void k0c_split_wo(
    const float* __restrict__ Wo, _Float16* __restrict__ W0,
    _Float16* __restrict__ W1)
{
    const int i = (blockIdx.x * 256 + threadIdx.x) * 4;
    float4 v = *(const float4*)(Wo + i);
    f16x4 h0, h1;
    h2pair s0 = split2(v.x); h0[0] = s0.h0; h1[0] = s0.h1;
    h2pair s1 = split2(v.y); h0[1] = s1.h0; h1[1] = s1.h1;
    h2pair s2 = split2(v.z); h0[2] = s2.h0; h1[2] = s2.h1;
    h2pair s3 = split2(v.w); h0[3] = s3.h0; h1[3] = s3.h1;
    *(f16x4*)&W0[i] = h0;
    *(f16x4*)&W1[i] = h1;
}

// ============================================================================
// k1: g[row] = sum_du Wp[du]*relu(enc[row,:].Wd[du,:] + bd[du])
// R4/R6's proven kernel, verbatim (260 us, MfmaUtil 36, occ 43%). Frozen.
// ============================================================================
__global__ __launch_bounds__(512, 4) void k1_weight_gemm(
    const float* __restrict__ enc, const _Float16* __restrict__ BT0,
    const _Float16* __restrict__ BT1, const float* __restrict__ bd,
    const float* __restrict__ Wp, float* __restrict__ g)
{
    // 2 buffers x (A0|A1|B0|B1 regions of 4096 halves) = 32768 halves = 64KB
    __shared__ __align__(16) _Float16 lds[32768];

    const int tid = threadIdx.x;
    const int lane = tid & 63;
    const int wv = tid >> 6;        // 0..7
    const int l5 = lane & 31;
    const int hi = lane >> 5;
    const int mtb = (wv & 1) * 64;  // M half
    const int ntb = (wv >> 1) * 32; // N quarter (32 du)

    // XCD-aware decode: xcd = bx%8; each xcd handles 32 row-groups x 8 du
    const int bx = blockIdx.x;
    const int xcd = bx & 7;
    const int j = bx >> 3;
    const int rg = xcd * 32 + (j >> 3);
    const int dug = j & 7;
    const long row0 = (long)rg * 128;
    const int du0 = dug * 128;

    // A staging: row sr = (wv>>2)*64 + lane, k-octet sq = wv&3 (wave-uniform)
    const int sgrp = wv >> 2;       // 0..1
    const int sq = wv & 3;          // 0..3
    const int sr = sgrp * 64 + lane;
    const float* aptr = enc + (row0 + sr) * (long)CDIM + sq * 8;
    const int aw0 = (sq * 128 + sr) * 8;   // A0 LDS write offset (halves)

    // B staging: wave stages quarter sq of plane sgrp (2 x gl_lds16 of 1KB)
    const _Float16* bsrc = (sgrp ? BT1 : BT0)
        + (size_t)(dug * 32) * 4096 + sq * 1024 + lane * 8;
    const int bldofs = 8192 + sgrp * 4096 + sq * 1024;

    f32x16 acc[2], accc[2];
#pragma unroll
    for (int mt = 0; mt < 2; mt++)
#pragma unroll
        for (int r = 0; r < 16; r++) { acc[mt][r] = 0.f; accc[mt][r] = 0.f; }

    float fa[8];

    // ---- prologue: stage tile 0 into buf0, prefetch fa(tile 1) ----
    *(float4*)&fa[0] = *(const float4*)(aptr + 0);
    *(float4*)&fa[4] = *(const float4*)(aptr + 4);
    gl_lds16(bsrc, &lds[bldofs]);
    gl_lds16(bsrc + 512, &lds[bldofs + 512]);
    asm volatile("" ::: "memory");
    {
        f16x8 h0, h1;
#pragma unroll
        for (int jj = 0; jj < 8; jj++) {
            h2pair s = split2(fa[jj]);
            h0[jj] = s.h0;
            h1[jj] = s.h1;
        }
        *(f16x8*)&lds[aw0] = h0;
        *(f16x8*)&lds[4096 + aw0] = h1;
    }
    *(float4*)&fa[0] = *(const float4*)(aptr + 32);
    *(float4*)&fa[4] = *(const float4*)(aptr + 36);
    asm volatile("s_waitcnt vmcnt(2) lgkmcnt(0)" ::: "memory");
    __builtin_amdgcn_s_barrier();

    for (int kt = 0; kt < 32; ++kt) {
        const int cur = (kt & 1) * 16384;
        const int nxt = cur ^ 16384;
        __builtin_amdgcn_sched_barrier(0);

        if (kt < 31) {
            // B(kt+1) DMA into nxt — in flight through this tile's MFMA
            const _Float16* bs = bsrc + (size_t)(kt + 1) * 4096;
            gl_lds16(bs, &lds[nxt + bldofs]);
            gl_lds16(bs + 512, &lds[nxt + bldofs + 512]);
            asm volatile("" ::: "memory");
            // split fa (= tile kt+1) into nxt A planes
            f16x8 h0, h1;
#pragma unroll
            for (int jj = 0; jj < 8; jj++) {
                h2pair s = split2(fa[jj]);
                h0[jj] = s.h0;
                h1[jj] = s.h1;
            }
            *(f16x8*)&lds[nxt + aw0] = h0;
            *(f16x8*)&lds[nxt + 4096 + aw0] = h1;
            if (kt < 30) {
                *(float4*)&fa[0] = *(const float4*)(aptr + (kt + 2) * 32);
                *(float4*)&fa[4] = *(const float4*)(aptr + (kt + 2) * 32 + 4);
            }
            asm volatile("" ::: "memory");
        }

        // ---- compute on cur: 2 phases (cq = p*2 + hi), 6 MFMA each ----
#pragma unroll
        for (int p = 0; p < 2; p++) {
            const int cq = p * 2 + hi;
            f16x8 A0[2], A1[2], B0, B1;
#pragma unroll
            for (int mt = 0; mt < 2; mt++) {
                const int ro = (cq * 128 + mtb + mt * 32 + l5) * 8;
                A0[mt] = *(const f16x8*)&lds[cur + ro];
                A1[mt] = *(const f16x8*)&lds[cur + 4096 + ro];
            }
            {
                const int ro = (cq * 128 + ntb + l5) * 8;
                B0 = *(const f16x8*)&lds[cur + 8192 + ro];
                B1 = *(const f16x8*)&lds[cur + 12288 + ro];
            }
            __builtin_amdgcn_s_setprio(1);
#pragma unroll
            for (int mt = 0; mt < 2; mt++) {
                acc[mt] = __builtin_amdgcn_mfma_f32_32x32x16_f16(
                    A0[mt], B0, acc[mt], 0, 0, 0);
                accc[mt] = __builtin_amdgcn_mfma_f32_32x32x16_f16(
                    A0[mt], B1, accc[mt], 0, 0, 0);
                accc[mt] = __builtin_amdgcn_mfma_f32_32x32x16_f16(
                    A1[mt], B0, accc[mt], 0, 0, 0);
            }
            __builtin_amdgcn_s_setprio(0);
        }

        // counted drain: B DMAs complete; fa prefetch stays in flight
        if (kt < 31) {
            if (kt < 30)
                asm volatile("s_waitcnt vmcnt(2) lgkmcnt(0)" ::: "memory");
            else
                asm volatile("s_waitcnt vmcnt(0) lgkmcnt(0)" ::: "memory");
            __builtin_amdgcn_s_barrier();
        }
    }

    // epilogue: h = relu(acc_total + bd[n]); g += Wp[n]*h reduced over n
    const float bdv = bd[du0 + ntb + l5];
    const float wpv = Wp[du0 + ntb + l5];
    float out = 0.f;
#pragma unroll
    for (int mt = 0; mt < 2; mt++)
#pragma unroll
        for (int r = 0; r < 16; r++) {
            float h = acc[mt][r] + 4.8828125e-4f * accc[mt][r] + bdv;
            h = h > 0.f ? h : 0.f;
            float s = wpv * h;
            s += __shfl_xor(s, 1);
            s += __shfl_xor(s, 2);
            s += __shfl_xor(s, 4);
            s += __shfl_xor(s, 8);
            s += __shfl_xor(s, 16);
            if (l5 == mt * 16 + r) out = s;
        }
    const int mt_sel = l5 >> 4;
    const int r_sel = l5 & 15;
    const int row = mtb + mt_sel * 32 + (r_sel & 3) + 8 * (r_sel >> 2) + 4 * hi;
    atomicAdd(&g[row0 + row], out);
}

// ============================================================================
// k2: per-batch sigmoid + masked sum + scale + sequential scan. (R6 verbatim)
// ============================================================================
__global__ __launch_bounds__(256) void k2_scan(
    const float* __restrict__ g, const int* __restrict__ in_len,
    const int* __restrict__ tgt_len, const float* __restrict__ bp,
    float* __restrict__ c_a, float* __restrict__ c_b,
    int* __restrict__ fire_t, int* __restrict__ n_fired,
    float* __restrict__ out_mask, float* __restrict__ out_dur,
    float* __restrict__ out_qty)
{
    __shared__ float w[TLEN];
    __shared__ float ca[TLEN];
    __shared__ float cb[TLEN];
    __shared__ int fires[MAXF];
    __shared__ float ssum[256];
    __shared__ float s_scale;
    __shared__ int s_nf;

    const int b = blockIdx.x;
    const int tid = threadIdx.x;
    const int len = in_len[b];
    const float bpv = bp[0];

    float local = 0.f;
    for (int t = tid; t < TLEN; t += 256) {
        float gv = g[b * TLEN + t] + bpv;
        float s = 1.f / (1.f + expf(-gv));
        float ow = (t < len) ? s : 0.f;
        w[t] = ow;
        local += ow;
    }
    ssum[tid] = local;
    __syncthreads();
    for (int st = 128; st > 0; st >>= 1) {
        if (tid < st) ssum[tid] += ssum[tid + st];
        __syncthreads();
    }
    if (tid == 0) {
        float org_sum = ssum[0];
        out_qty[b] = org_sum;
        s_scale = (float)tgt_len[b] / (org_sum + 1e-8f);
    }
    __syncthreads();
    float scale = s_scale;
    for (int t = tid; t < TLEN; t += 256) w[t] *= scale;
    __syncthreads();

    if (tid == 0) {
        float accw = 0.f;
        int k = 0;
        int t = 0;
        for (; t + 8 <= len; t += 8) {
            float4 wa = *(const float4*)&w[t];
            float4 wb4 = *(const float4*)&w[t + 4];
            float wv8[8] = {wa.x, wa.y, wa.z, wa.w, wb4.x, wb4.y, wb4.z, wb4.w};
#pragma unroll
            for (int u = 0; u < 8; u++) {
                float wt = wv8[u];
                float aw = accw + wt;
                bool f = (aw >= 1.0f);
                float rem = 1.0f - accw;          // exact reference order
                float fb = wt - rem;
                ca[t + u] = f ? rem : wt;
                cb[t + u] = f ? fb : 0.f;
                fires[k & (MAXF - 1)] = t + u;    // commits on fire
                k += f ? 1 : 0;
                accw = f ? fb : aw;
            }
        }
        for (; t < len; t++) {
            float wt = w[t];
            float aw = accw + wt;
            bool f = (aw >= 1.0f);
            float rem = 1.0f - accw;
            float fb = wt - rem;
            ca[t] = f ? rem : wt;
            cb[t] = f ? fb : 0.f;
            fires[k & (MAXF - 1)] = t;
            k += f ? 1 : 0;
            accw = f ? fb : aw;
        }
        s_nf = (k < MAXF) ? k : MAXF;
        n_fired[b] = s_nf;
    }
    __syncthreads();

    for (int t = tid; t < len; t += 256) {
        c_a[b * TLEN + t] = ca[t];
        c_b[b * TLEN + t] = cb[t];
    }
    const int nf = s_nf;
    for (int jj = tid; jj < nf; jj += 256) {
        int tj = fires[jj];
        fire_t[b * MAXF + jj] = tj;
        out_mask[b * TLEN + jj] = 1.0f;
        int prev = (jj == 0) ? 0 : fires[jj - 1];
        out_dur[b * TLEN + jj] = (float)(tj - prev);
    }
    if (tid == 0 && nf == 0) out_mask[b * TLEN] = 1.0f;
}

// ============================================================================
// k3a: compact fired frames (segmented weighted sums, ascending t), writing
// fp16 split planes row-major [b][frame][k]; rows >= n_fired zero-filled.
// ============================================================================
__global__ __launch_bounds__(256) void k3a_compact(
    const float* __restrict__ enc, const float* __restrict__ c_a,
    const float* __restrict__ c_b, const int* __restrict__ fire_t,
    const int* __restrict__ n_fired, _Float16* __restrict__ C0,
    _Float16* __restrict__ C1)
{
    const int b = blockIdx.y;
    const int k = blockIdx.x;
    const int tid = threadIdx.x;
    _Float16* d0 = C0 + ((size_t)b * MAXF + k) * CDIM + tid * 4;
    _Float16* d1 = C1 + ((size_t)b * MAXF + k) * CDIM + tid * 4;
    if (k >= n_fired[b]) {
        f16x4 z = {(_Float16)0.f, (_Float16)0.f, (_Float16)0.f, (_Float16)0.f};
        *(f16x4*)d0 = z;
        *(f16x4*)d1 = z;
        return;
    }
    const int tend = fire_t[b * MAXF + k];
    const int tprev = (k == 0) ? -1 : fire_t[b * MAXF + k - 1];
    float ax = 0.f, ay = 0.f, az = 0.f, aw = 0.f;
    const int tstart = (tprev < 0) ? 0 : tprev;
    for (int t = tstart; t <= tend; t++) {
        float coef = (t == tprev) ? c_b[b * TLEN + t] : c_a[b * TLEN + t];
        const float4 e = *(const float4*)(enc + ((size_t)b * TLEN + t) * CDIM + tid * 4);
        ax += coef * e.x;
        ay += coef * e.y;
        az += coef * e.z;
        aw += coef * e.w;
    }
    f16x4 h0, h1;
    h2pair s0 = split2(ax); h0[0] = s0.h0; h1[0] = s0.h1;
    h2pair s1 = split2(ay); h0[1] = s1.h0; h1[1] = s1.h1;
    h2pair s2 = split2(az); h0[2] = s2.h0; h1[2] = s2.h1;
    h2pair s3 = split2(aw); h0[3] = s3.h0; h1[3] = s3.h1;
    *(f16x4*)d0 = h0;
    *(f16x4*)d1 = h1;
}

// ============================================================================
// k3b: cif_outputs[b,j,o] = compact[b,j,:].Wo[o,:] — fp16-3 MFMA.
// R6 structure (BM=64, wave tile 64x32, grid (8,4,16)) + DOUBLE-BUFFERED LDS:
// 2 x 24 KB ping-pong, ONE barrier per K-step (was 2). Global loads for
// kt+1 issued before compute(kt) (latency hides under 12 MFMAs); ds_writes
// to the other buffer after. Reads of buf[cur] are consumed by MFMAs before
// the barrier (compiler lgkmcnt), so the single-barrier pattern is race-free
// (same discipline as k1). Compute/epilogue bit-identical to R6.
// ============================================================================
__global__ __launch_bounds__(256) void k3b_outproj(
    const _Float16* __restrict__ C0, const _Float16* __restrict__ C1,
    const _Float16* __restrict__ W0, const _Float16* __restrict__ W1,
    const int* __restrict__ n_fired, float* __restrict__ out0)
{
    // per buffer: A0[0,2048) A1[2048,4096) B0[4096,8192) B1[8192,12288)
    // 2 buffers x 12288 halves = 48 KB
    __shared__ __align__(16) _Float16 lds[24576];

    const int b = blockIdx.z;
    const int nf = n_fired[b];
    const int j0 = blockIdx.x * 64;
    if (j0 >= nf) return;
    const int o0 = blockIdx.y * 128;
    const int tid = threadIdx.x;
    const int lane = tid & 63;
    const int wv = tid >> 6;        // 0..3
    const int l5 = lane & 31;
    const int hi = lane >> 5;
    const int ntb = wv * 32;        // N quarter

    // B staging: 128 rows, 2 k-halves, 2 chunks
    const int sr = tid >> 1;
    const int sh = tid & 1;
    const _Float16* b0p = W0 + (size_t)(o0 + sr) * CDIM + sh * 16;
    const _Float16* b1p = W1 + (size_t)(o0 + sr) * CDIM + sh * 16;
    const int bwofs = (sh * 2 * 128 + sr) * 8;     // chunk c adds c*1024
    // A staging: 64 rows, 4 k-octets, 1 f16x8 per plane per thread
    const int ar = tid >> 2;
    const int aq = tid & 3;
    const _Float16* a0p = C0 + ((size_t)b * MAXF + j0 + ar) * CDIM + aq * 8;
    const _Float16* a1p = C1 + ((size_t)b * MAXF + j0 + ar) * CDIM + aq * 8;
    const int awofs = (aq * 64 + ar) * 8;

    f32x16 acc[2], accc[2];
#pragma unroll
    for (int mt = 0; mt < 2; mt++)
#pragma unroll
        for (int r = 0; r < 16; r++) { acc[mt][r] = 0.f; accc[mt][r] = 0.f; }

    f16x8 xa0, xa1, xb0[2], xb1[2];
    // load tile 0 to regs
    xa0 = *(const f16x8*)(a0p);
    xa1 = *(const f16x8*)(a1p);
#pragma unroll
    for (int c = 0; c < 2; c++) {
        xb0[c] = *(const f16x8*)(b0p + c * 8);
        xb1[c] = *(const f16x8*)(b1p + c * 8);
    }
    // write tile 0 into buffer 0
    *(f16x8*)&lds[awofs] = xa0;
    *(f16x8*)&lds[2048 + awofs] = xa1;
#pragma unroll
    for (int c = 0; c < 2; c++) {
        *(f16x8*)&lds[4096 + bwofs + c * 1024] = xb0[c];
        *(f16x8*)&lds[8192 + bwofs + c * 1024] = xb1[c];
    }

    for (int kt = 0; kt < 32; ++kt) {
        const int cur = (kt & 1) * 12288;
        const int nxt = cur ^ 12288;
        __syncthreads();   // buf[cur] writes visible; buf[nxt] fully consumed

        // issue global loads for tile kt+1 (land during compute)
        if (kt < 31) {
            const int o = (kt + 1) * 32;
            xa0 = *(const f16x8*)(a0p + o);
            xa1 = *(const f16x8*)(a1p + o);
#pragma unroll
            for (int c = 0; c < 2; c++) {
                xb0[c] = *(const f16x8*)(b0p + o + c * 8);
                xb1[c] = *(const f16x8*)(b1p + o + c * 8);
            }
        }

        // compute on buf[cur]
#pragma unroll
        for (int ks = 0; ks < 2; ks++) {
            const int ch = ks * 2 + hi;
            f16x8 A0[2], A1[2], B0, B1;
#pragma unroll
            for (int mt = 0; mt < 2; mt++) {
                const int ro = (ch * 64 + mt * 32 + l5) * 8;
                A0[mt] = *(const f16x8*)&lds[cur + ro];
                A1[mt] = *(const f16x8*)&lds[cur + 2048 + ro];
            }
            {
                const int ro = (ch * 128 + ntb + l5) * 8;
                B0 = *(const f16x8*)&lds[cur + 4096 + ro];
                B1 = *(const f16x8*)&lds[cur + 8192 + ro];
            }
#pragma unroll
            for (int mt = 0; mt < 2; mt++) {
                acc[mt] = __builtin_amdgcn_mfma_f32_32x32x16_f16(
                    A0[mt], B0, acc[mt], 0, 0, 0);
                accc[mt] = __builtin_amdgcn_mfma_f32_32x32x16_f16(
                    A0[mt], B1, accc[mt], 0, 0, 0);
                accc[mt] = __builtin_amdgcn_mfma_f32_32x32x16_f16(
                    A1[mt], B0, accc[mt], 0, 0, 0);
            }
        }

        // write tile kt+1 into buf[nxt] (compiler waits vmcnt on xa/xb)
        if (kt < 31) {
            *(f16x8*)&lds[nxt + awofs] = xa0;
            *(f16x8*)&lds[nxt + 2048 + awofs] = xa1;
#pragma unroll
            for (int c = 0; c < 2; c++) {
                *(f16x8*)&lds[nxt + 4096 + bwofs + c * 1024] = xb0[c];
                *(f16x8*)&lds[nxt + 8192 + bwofs + c * 1024] = xb1[c];
            }
        }
    }

#pragma unroll
    for (int mt = 0; mt < 2; mt++)
#pragma unroll
        for (int r = 0; r < 16; r++) {
            float val = acc[mt][r] + 4.8828125e-4f * accc[mt][r];
            int m = mt * 32 + (r & 3) + 8 * (r >> 2) + 4 * hi;
            int col = o0 + ntb + l5;
            out0[((size_t)b * TLEN + j0 + m) * OUTDIM + col] = val;
        }
}

// ============================================================================
// Host launch — R6 layout restored (memsets + separate k0a/k0c).
// ============================================================================
extern "C" void kernel_launch(void* const* d_in, const int* in_sizes, int n_in,
                              void* d_out, int out_size, void* d_ws, size_t ws_size,
                              hipStream_t stream)
{
    const float* enc = (const float*)d_in[0];
    const int* in_len = (const int*)d_in[1];
    const int* tgt_len = (const int*)d_in[2];
    const float* Wd = (const float*)d_in[3];
    const float* bd = (const float*)d_in[4];
    const float* Wp = (const float*)d_in[5];
    const float* bp = (const float*)d_in[6];
    const float* Wo = (const float*)d_in[7];

    char* ws = (char*)d_ws;
    float* g       = (float*)(ws + 0);             // 128 KB
    float* c_a     = (float*)(ws + 131072);        // 128 KB
    float* c_b     = (float*)(ws + 262144);        // 128 KB
    int* fire_t    = (int*)(ws + 393216);          // 32 KB
    int* n_fired   = (int*)(ws + 425984);          // 64 B
    _Float16* WdT0 = (_Float16*)(ws + 458752);     // 2 MB tiled
    _Float16* WdT1 = (_Float16*)(ws + 2555904);    // 2 MB
    _Float16* Wo0  = (_Float16*)(ws + 4653056);    // 1 MB row-major
    _Float16* Wo1  = (_Float16*)(ws + 5701632);    // 1 MB
    _Float16* C0   = (_Float16*)(ws + 6750208);    // 16 MB
    _Float16* C1   = (_Float16*)(ws + 23527424);   // 16 MB  (end ~40.3 MB)

    float* out0 = (float*)d_out;
    float* out_mask = out0 + (size_t)BSZ * TLEN * OUTDIM;
    float* out_dur = out_mask + (size_t)BSZ * TLEN;
    float* out_qty = out_dur + (size_t)BSZ * TLEN;

    (void)hipMemsetAsync(g, 0, 131072, stream);
    (void)hipMemsetAsync(d_out, 0, (size_t)out_size * 4, stream);

    k0a_split_wd<<<dim3(8, 32), 128, 0, stream>>>(Wd, WdT0, WdT1);
    k0c_split_wo<<<512, 256, 0, stream>>>(Wo, Wo0, Wo1);
    k1_weight_gemm<<<2048, 512, 0, stream>>>(enc, WdT0, WdT1, bd, Wp, g);
    k2_scan<<<BSZ, 256, 0, stream>>>(g, in_len, tgt_len, bp, c_a, c_b,
                                     fire_t, n_fired, out_mask, out_dur, out_qty);
    k3a_compact<<<dim3(MAXF, BSZ), 256, 0, stream>>>(enc, c_a, c_b, fire_t,
                                                     n_fired, C0, C1);
    k3b_outproj<<<dim3(8, 4, BSZ), 256, 0, stream>>>(C0, C1, Wo0, Wo1,
                                                     n_fired, out0);
}

// Round 9
// 585.555 us; speedup vs baseline: 1.0973x; 1.0113x over previous
//
#include <hip/hip_runtime.h>
#include <cstdint>
#include <cstddef>

#define BSZ 16
#define TLEN 2048
#define CDIM 1024
#define OUTDIM 512
#define MAXF 512

typedef _Float16 f16x8 __attribute__((ext_vector_type(8)));
typedef _Float16 f16x4 __attribute__((ext_vector_type(4)));
typedef float f32x16 __attribute__((ext_vector_type(16)));

__device__ __forceinline__ void gl_lds16(const void* g, void* l) {
    __builtin_amdgcn_global_load_lds(
        (const __attribute__((address_space(1))) void*)g,
        (__attribute__((address_space(3))) void*)l, 16, 0, 0);
}

// exact 2-term fp16 split: a = h0 + h1 * 2^-11  (h1 pre-scaled by 2^11)
struct h2pair { _Float16 h0, h1; };
__device__ __forceinline__ h2pair split2(float a) {
    h2pair o;
    o.h0 = (_Float16)a;
    float r = a - (float)o.h0;       // exact (Sterbenz)
    o.h1 = (_Float16)(r * 2048.0f);
    return o;
}

// ============================================================================
// k0a: split Wd into 2 fp16 planes in k1's TILED layout:
// plane[(dut*32+ktl)*4096 + (c*128 + r)*8 + j] = Wd[dut*128+r][ktl*32+c*8+j]
// ============================================================================
__global__ __launch_bounds__(128) void k0a_split_wd(
    const float* __restrict__ Wd, _Float16* __restrict__ B0,
    _Float16* __restrict__ B1)
{
    const int dut = blockIdx.x;     // 8
    const int ktl = blockIdx.y;     // 32
    const int r = threadIdx.x;      // 128
    const float* src = Wd + (size_t)(dut * 128 + r) * CDIM + ktl * 32;
    float v[32];
#pragma unroll
    for (int j = 0; j < 8; j++) *(float4*)&v[j * 4] = *(const float4*)(src + j * 4);
    const size_t tb = (size_t)(dut * 32 + ktl) * 4096;
#pragma unroll
    for (int c = 0; c < 4; c++) {
        f16x8 h0, h1;
#pragma unroll
        for (int j = 0; j < 8; j++) {
            h2pair s = split2(v[c * 8 + j]);
            h0[j] = s.h0;
            h1[j] = s.h1;
        }
        *(f16x8*)&B0[tb + (c * 128 + r) * 8] = h0;
        *(f16x8*)&B1[tb + (c * 128 + r) * 8] = h1;
    }
}

// ============================================================================
// k0c: split Wo into 2 fp16 planes, row-major [o][k]
// ============================================================================
__global__ __launch_bounds__(256) void k0c_split_wo(
    const float* __restrict__ Wo, _Float16* __restrict__ W0,
    _Float16* __restrict__ W1)
{
    const int i = (blockIdx.x * 256 + threadIdx.x) * 4;
    float4 v = *(const float4*)(Wo + i);
    f16x4 h0, h1;
    h2pair s0 = split2(v.x); h0[0] = s0.h0; h1[0] = s0.h1;
    h2pair s1 = split2(v.y); h0[1] = s1.h0; h1[1] = s1.h1;
    h2pair s2 = split2(v.z); h0[2] = s2.h0; h1[2] = s2.h1;
    h2pair s3 = split2(v.w); h0[3] = s3.h0; h1[3] = s3.h1;
    *(f16x4*)&W0[i] = h0;
    *(f16x4*)&W1[i] = h1;
}

// ============================================================================
// k1: g[row] = sum_du Wp[du]*relu(enc[row,:].Wd[du,:] + bd[du])
// R6 structure with the two INTRA-STEP fences relaxed: the region between
// {gl_lds B -> fence1} and {fence2 -> vmcnt(2) drain} is now one free
// scheduling window containing the A-split VALU, ds_writes, fa loads, AND
// both MFMA phases -- the compiler can co-schedule staging under the MFMA
// shadow (m114: VALU and MFMA pipes overlap). Drain counting unchanged:
// at vmcnt(2), outstanding = 2 B-DMAs (pre-fence1, oldest) + 2 fa loads
// (in-region) -> exactly the B-DMAs drain. sched_barrier(0) at loop top
// still blocks hoisting ds_reads of buf[cur] above the barrier; fence2 +
// lgkmcnt(0) still pins ds_writes before the end barrier. Accumulation
// order bit-identical (absmax must stay 6.0).
// ============================================================================
__global__ __launch_bounds__(512, 4) void k1_weight_gemm(
    const float* __restrict__ enc, const _Float16* __restrict__ BT0,
    const _Float16* __restrict__ BT1, const float* __restrict__ bd,
    const float* __restrict__ Wp, float* __restrict__ g)
{
    // 2 buffers x (A0|A1|B0|B1 regions of 4096 halves) = 32768 halves = 64KB
    __shared__ __align__(16) _Float16 lds[32768];

    const int tid = threadIdx.x;
    const int lane = tid & 63;
    const int wv = tid >> 6;        // 0..7
    const int l5 = lane & 31;
    const int hi = lane >> 5;
    const int mtb = (wv & 1) * 64;  // M half
    const int ntb = (wv >> 1) * 32; // N quarter (32 du)

    // XCD-aware decode: xcd = bx%8; each xcd handles 32 row-groups x 8 du
    const int bx = blockIdx.x;
    const int xcd = bx & 7;
    const int j = bx >> 3;
    const int rg = xcd * 32 + (j >> 3);
    const int dug = j & 7;
    const long row0 = (long)rg * 128;
    const int du0 = dug * 128;

    // A staging: row sr = (wv>>2)*64 + lane, k-octet sq = wv&3 (wave-uniform)
    const int sgrp = wv >> 2;       // 0..1
    const int sq = wv & 3;          // 0..3
    const int sr = sgrp * 64 + lane;
    const float* aptr = enc + (row0 + sr) * (long)CDIM + sq * 8;
    const int aw0 = (sq * 128 + sr) * 8;   // A0 LDS write offset (halves)

    // B staging: wave stages quarter sq of plane sgrp (2 x gl_lds16 of 1KB)
    const _Float16* bsrc = (sgrp ? BT1 : BT0)
        + (size_t)(dug * 32) * 4096 + sq * 1024 + lane * 8;
    const int bldofs = 8192 + sgrp * 4096 + sq * 1024;

    f32x16 acc[2], accc[2];
#pragma unroll
    for (int mt = 0; mt < 2; mt++)
#pragma unroll
        for (int r = 0; r < 16; r++) { acc[mt][r] = 0.f; accc[mt][r] = 0.f; }

    float fa[8];

    // ---- prologue: stage tile 0 into buf0, prefetch fa(tile 1) ----
    *(float4*)&fa[0] = *(const float4*)(aptr + 0);
    *(float4*)&fa[4] = *(const float4*)(aptr + 4);
    gl_lds16(bsrc, &lds[bldofs]);
    gl_lds16(bsrc + 512, &lds[bldofs + 512]);
    asm volatile("" ::: "memory");
    {
        f16x8 h0, h1;
#pragma unroll
        for (int jj = 0; jj < 8; jj++) {
            h2pair s = split2(fa[jj]);
            h0[jj] = s.h0;
            h1[jj] = s.h1;
        }
        *(f16x8*)&lds[aw0] = h0;
        *(f16x8*)&lds[4096 + aw0] = h1;
    }
    *(float4*)&fa[0] = *(const float4*)(aptr + 32);
    *(float4*)&fa[4] = *(const float4*)(aptr + 36);
    asm volatile("s_waitcnt vmcnt(2) lgkmcnt(0)" ::: "memory");
    __builtin_amdgcn_s_barrier();

    for (int kt = 0; kt < 32; ++kt) {
        const int cur = (kt & 1) * 16384;
        const int nxt = cur ^ 16384;
        __builtin_amdgcn_sched_barrier(0);

        // B(kt+1) DMA into nxt — oldest VMEM ops of this step (fence pins)
        if (kt < 31) {
            const _Float16* bs = bsrc + (size_t)(kt + 1) * 4096;
            gl_lds16(bs, &lds[nxt + bldofs]);
            gl_lds16(bs + 512, &lds[nxt + bldofs + 512]);
        }
        asm volatile("" ::: "memory");   // fence1: fa loads stay younger

        // ---- free scheduling region: staging + compute interleaved ----
        if (kt < 31) {
            // split fa (= tile kt+1) into nxt A planes
            f16x8 h0, h1;
#pragma unroll
            for (int jj = 0; jj < 8; jj++) {
                h2pair s = split2(fa[jj]);
                h0[jj] = s.h0;
                h1[jj] = s.h1;
            }
            *(f16x8*)&lds[nxt + aw0] = h0;
            *(f16x8*)&lds[nxt + 4096 + aw0] = h1;
            if (kt < 30) {
                *(float4*)&fa[0] = *(const float4*)(aptr + (kt + 2) * 32);
                *(float4*)&fa[4] = *(const float4*)(aptr + (kt + 2) * 32 + 4);
            }
        }

        // compute on cur: 2 phases (cq = p*2 + hi), 6 MFMA each
#pragma unroll
        for (int p = 0; p < 2; p++) {
            const int cq = p * 2 + hi;
            f16x8 A0[2], A1[2], B0, B1;
#pragma unroll
            for (int mt = 0; mt < 2; mt++) {
                const int ro = (cq * 128 + mtb + mt * 32 + l5) * 8;
                A0[mt] = *(const f16x8*)&lds[cur + ro];
                A1[mt] = *(const f16x8*)&lds[cur + 4096 + ro];
            }
            {
                const int ro = (cq * 128 + ntb + l5) * 8;
                B0 = *(const f16x8*)&lds[cur + 8192 + ro];
                B1 = *(const f16x8*)&lds[cur + 12288 + ro];
            }
            __builtin_amdgcn_s_setprio(1);
#pragma unroll
            for (int mt = 0; mt < 2; mt++) {
                acc[mt] = __builtin_amdgcn_mfma_f32_32x32x16_f16(
                    A0[mt], B0, acc[mt], 0, 0, 0);
                accc[mt] = __builtin_amdgcn_mfma_f32_32x32x16_f16(
                    A0[mt], B1, accc[mt], 0, 0, 0);
                accc[mt] = __builtin_amdgcn_mfma_f32_32x32x16_f16(
                    A1[mt], B0, accc[mt], 0, 0, 0);
            }
            __builtin_amdgcn_s_setprio(0);
        }

        // fence2 + counted drain: B DMAs complete; fa prefetch stays in flight
        if (kt < 31) {
            asm volatile("" ::: "memory");
            if (kt < 30)
                asm volatile("s_waitcnt vmcnt(2) lgkmcnt(0)" ::: "memory");
            else
                asm volatile("s_waitcnt vmcnt(0) lgkmcnt(0)" ::: "memory");
            __builtin_amdgcn_s_barrier();
        }
    }

    // epilogue: h = relu(acc_total + bd[n]); g += Wp[n]*h reduced over n
    const float bdv = bd[du0 + ntb + l5];
    const float wpv = Wp[du0 + ntb + l5];
    float out = 0.f;
#pragma unroll
    for (int mt = 0; mt < 2; mt++)
#pragma unroll
        for (int r = 0; r < 16; r++) {
            float h = acc[mt][r] + 4.8828125e-4f * accc[mt][r] + bdv;
            h = h > 0.f ? h : 0.f;
            float s = wpv * h;
            s += __shfl_xor(s, 1);
            s += __shfl_xor(s, 2);
            s += __shfl_xor(s, 4);
            s += __shfl_xor(s, 8);
            s += __shfl_xor(s, 16);
            if (l5 == mt * 16 + r) out = s;
        }
    const int mt_sel = l5 >> 4;
    const int r_sel = l5 & 15;
    const int row = mtb + mt_sel * 32 + (r_sel & 3) + 8 * (r_sel >> 2) + 4 * hi;
    atomicAdd(&g[row0 + row], out);
}

// ============================================================================
// k2: per-batch sigmoid + masked sum + scale + sequential scan. (R6 verbatim)
// ============================================================================
__global__ __launch_bounds__(256) void k2_scan(
    const float* __restrict__ g, const int* __restrict__ in_len,
    const int* __restrict__ tgt_len, const float* __restrict__ bp,
    float* __restrict__ c_a, float* __restrict__ c_b,
    int* __restrict__ fire_t, int* __restrict__ n_fired,
    float* __restrict__ out_mask, float* __restrict__ out_dur,
    float* __restrict__ out_qty)
{
    __shared__ float w[TLEN];
    __shared__ float ca[TLEN];
    __shared__ float cb[TLEN];
    __shared__ int fires[MAXF];
    __shared__ float ssum[256];
    __shared__ float s_scale;
    __shared__ int s_nf;

    const int b = blockIdx.x;
    const int tid = threadIdx.x;
    const int len = in_len[b];
    const float bpv = bp[0];

    float local = 0.f;
    for (int t = tid; t < TLEN; t += 256) {
        float gv = g[b * TLEN + t] + bpv;
        float s = 1.f / (1.f + expf(-gv));
        float ow = (t < len) ? s : 0.f;
        w[t] = ow;
        local += ow;
    }
    ssum[tid] = local;
    __syncthreads();
    for (int st = 128; st > 0; st >>= 1) {
        if (tid < st) ssum[tid] += ssum[tid + st];
        __syncthreads();
    }
    if (tid == 0) {
        float org_sum = ssum[0];
        out_qty[b] = org_sum;
        s_scale = (float)tgt_len[b] / (org_sum + 1e-8f);
    }
    __syncthreads();
    float scale = s_scale;
    for (int t = tid; t < TLEN; t += 256) w[t] *= scale;
    __syncthreads();

    if (tid == 0) {
        float accw = 0.f;
        int k = 0;
        int t = 0;
        for (; t + 8 <= len; t += 8) {
            float4 wa = *(const float4*)&w[t];
            float4 wb4 = *(const float4*)&w[t + 4];
            float wv8[8] = {wa.x, wa.y, wa.z, wa.w, wb4.x, wb4.y, wb4.z, wb4.w};
#pragma unroll
            for (int u = 0; u < 8; u++) {
                float wt = wv8[u];
                float aw = accw + wt;
                bool f = (aw >= 1.0f);
                float rem = 1.0f - accw;          // exact reference order
                float fb = wt - rem;
                ca[t + u] = f ? rem : wt;
                cb[t + u] = f ? fb : 0.f;
                fires[k & (MAXF - 1)] = t + u;    // commits on fire
                k += f ? 1 : 0;
                accw = f ? fb : aw;
            }
        }
        for (; t < len; t++) {
            float wt = w[t];
            float aw = accw + wt;
            bool f = (aw >= 1.0f);
            float rem = 1.0f - accw;
            float fb = wt - rem;
            ca[t] = f ? rem : wt;
            cb[t] = f ? fb : 0.f;
            fires[k & (MAXF - 1)] = t;
            k += f ? 1 : 0;
            accw = f ? fb : aw;
        }
        s_nf = (k < MAXF) ? k : MAXF;
        n_fired[b] = s_nf;
    }
    __syncthreads();

    for (int t = tid; t < len; t += 256) {
        c_a[b * TLEN + t] = ca[t];
        c_b[b * TLEN + t] = cb[t];
    }
    const int nf = s_nf;
    for (int jj = tid; jj < nf; jj += 256) {
        int tj = fires[jj];
        fire_t[b * MAXF + jj] = tj;
        out_mask[b * TLEN + jj] = 1.0f;
        int prev = (jj == 0) ? 0 : fires[jj - 1];
        out_dur[b * TLEN + jj] = (float)(tj - prev);
    }
    if (tid == 0 && nf == 0) out_mask[b * TLEN] = 1.0f;
}

// ============================================================================
// k3a: compact fired frames (segmented weighted sums, ascending t), writing
// fp16 split planes row-major [b][frame][k]; rows >= n_fired zero-filled.
// ============================================================================
__global__ __launch_bounds__(256) void k3a_compact(
    const float* __restrict__ enc, const float* __restrict__ c_a,
    const float* __restrict__ c_b, const int* __restrict__ fire_t,
    const int* __restrict__ n_fired, _Float16* __restrict__ C0,
    _Float16* __restrict__ C1)
{
    const int b = blockIdx.y;
    const int k = blockIdx.x;
    const int tid = threadIdx.x;
    _Float16* d0 = C0 + ((size_t)b * MAXF + k) * CDIM + tid * 4;
    _Float16* d1 = C1 + ((size_t)b * MAXF + k) * CDIM + tid * 4;
    if (k >= n_fired[b]) {
        f16x4 z = {(_Float16)0.f, (_Float16)0.f, (_Float16)0.f, (_Float16)0.f};
        *(f16x4*)d0 = z;
        *(f16x4*)d1 = z;
        return;
    }
    const int tend = fire_t[b * MAXF + k];
    const int tprev = (k == 0) ? -1 : fire_t[b * MAXF + k - 1];
    float ax = 0.f, ay = 0.f, az = 0.f, aw = 0.f;
    const int tstart = (tprev < 0) ? 0 : tprev;
    for (int t = tstart; t <= tend; t++) {
        float coef = (t == tprev) ? c_b[b * TLEN + t] : c_a[b * TLEN + t];
        const float4 e = *(const float4*)(enc + ((size_t)b * TLEN + t) * CDIM + tid * 4);
        ax += coef * e.x;
        ay += coef * e.y;
        az += coef * e.z;
        aw += coef * e.w;
    }
    f16x4 h0, h1;
    h2pair s0 = split2(ax); h0[0] = s0.h0; h1[0] = s0.h1;
    h2pair s1 = split2(ay); h0[1] = s1.h0; h1[1] = s1.h1;
    h2pair s2 = split2(az); h0[2] = s2.h0; h1[2] = s2.h1;
    h2pair s3 = split2(aw); h0[3] = s3.h0; h1[3] = s3.h1;
    *(f16x4*)d0 = h0;
    *(f16x4*)d1 = h1;
}

// ============================================================================
// k3b: cif_outputs[b,j,o] = compact[b,j,:].Wo[o,:] — fp16-3 MFMA.
// R6 version (BM=64, wave tile 64x32, grid (8,4,16), 24 KB LDS, 2 barriers
// per K-step) — measured best-total configuration; R8's dbuf was neutral.
// ============================================================================
__global__ __launch_bounds__(256) void k3b_outproj(
    const _Float16* __restrict__ C0, const _Float16* __restrict__ C1,
    const _Float16* __restrict__ W0, const _Float16* __restrict__ W1,
    const int* __restrict__ n_fired, float* __restrict__ out0)
{
    // A0[0,2048) A1[2048,4096) B0[4096,8192) B1[8192,12288) halves = 24 KB
    __shared__ __align__(16) _Float16 lds[12288];

    const int b = blockIdx.z;
    const int nf = n_fired[b];
    const int j0 = blockIdx.x * 64;
    if (j0 >= nf) return;
    const int o0 = blockIdx.y * 128;
    const int tid = threadIdx.x;
    const int lane = tid & 63;
    const int wv = tid >> 6;        // 0..3
    const int l5 = lane & 31;
    const int hi = lane >> 5;
    const int ntb = wv * 32;        // N quarter

    // B staging: 128 rows, 2 k-halves, 2 chunks
    const int sr = tid >> 1;
    const int sh = tid & 1;
    const _Float16* b0p = W0 + (size_t)(o0 + sr) * CDIM + sh * 16;
    const _Float16* b1p = W1 + (size_t)(o0 + sr) * CDIM + sh * 16;
    // A staging: 64 rows, 4 k-octets, 1 f16x8 per plane per thread
    const int ar = tid >> 2;
    const int aq = tid & 3;
    const _Float16* a0p = C0 + ((size_t)b * MAXF + j0 + ar) * CDIM + aq * 8;
    const _Float16* a1p = C1 + ((size_t)b * MAXF + j0 + ar) * CDIM + aq * 8;
    const int awofs = (aq * 64 + ar) * 8;

    f32x16 acc[2], accc[2];
#pragma unroll
    for (int mt = 0; mt < 2; mt++)
#pragma unroll
        for (int r = 0; r < 16; r++) { acc[mt][r] = 0.f; accc[mt][r] = 0.f; }

    f16x8 xa0, xa1, xb0[2], xb1[2];
    xa0 = *(const f16x8*)(a0p);
    xa1 = *(const f16x8*)(a1p);
#pragma unroll
    for (int c = 0; c < 2; c++) {
        xb0[c] = *(const f16x8*)(b0p + c * 8);
        xb1[c] = *(const f16x8*)(b1p + c * 8);
    }

    for (int kt = 0; kt < 32; ++kt) {
        __syncthreads();
        *(f16x8*)&lds[awofs] = xa0;
        *(f16x8*)&lds[2048 + awofs] = xa1;
#pragma unroll
        for (int c = 0; c < 2; c++) {
            *(f16x8*)&lds[4096 + ((sh * 2 + c) * 128 + sr) * 8] = xb0[c];
            *(f16x8*)&lds[8192 + ((sh * 2 + c) * 128 + sr) * 8] = xb1[c];
        }
        __syncthreads();
        if (kt < 31) {
            const int o = (kt + 1) * 32;
            xa0 = *(const f16x8*)(a0p + o);
            xa1 = *(const f16x8*)(a1p + o);
#pragma unroll
            for (int c = 0; c < 2; c++) {
                xb0[c] = *(const f16x8*)(b0p + o + c * 8);
                xb1[c] = *(const f16x8*)(b1p + o + c * 8);
            }
        }
#pragma unroll
        for (int ks = 0; ks < 2; ks++) {
            const int ch = ks * 2 + hi;
            f16x8 A0[2], A1[2], B0, B1;
#pragma unroll
            for (int mt = 0; mt < 2; mt++) {
                const int ro = (ch * 64 + mt * 32 + l5) * 8;
                A0[mt] = *(const f16x8*)&lds[ro];
                A1[mt] = *(const f16x8*)&lds[2048 + ro];
            }
            {
                const int ro = (ch * 128 + ntb + l5) * 8;
                B0 = *(const f16x8*)&lds[4096 + ro];
                B1 = *(const f16x8*)&lds[8192 + ro];
            }
#pragma unroll
            for (int mt = 0; mt < 2; mt++) {
                acc[mt] = __builtin_amdgcn_mfma_f32_32x32x16_f16(
                    A0[mt], B0, acc[mt], 0, 0, 0);
                accc[mt] = __builtin_amdgcn_mfma_f32_32x32x16_f16(
                    A0[mt], B1, accc[mt], 0, 0, 0);
                accc[mt] = __builtin_amdgcn_mfma_f32_32x32x16_f16(
                    A1[mt], B0, accc[mt], 0, 0, 0);
            }
        }
    }

#pragma unroll
    for (int mt = 0; mt < 2; mt++)
#pragma unroll
        for (int r = 0; r < 16; r++) {
            float val = acc[mt][r] + 4.8828125e-4f * accc[mt][r];
            int m = mt * 32 + (r & 3) + 8 * (r >> 2) + 4 * hi;
            int col = o0 + ntb + l5;
            out0[((size_t)b * TLEN + j0 + m) * OUTDIM + col] = val;
        }
}

// ============================================================================
// Host launch — R6 layout (memsets + separate k0a/k0c).
// ============================================================================
extern "C" void kernel_launch(void* const* d_in, const int* in_sizes, int n_in,
                              void* d_out, int out_size, void* d_ws, size_t ws_size,
                              hipStream_t stream)
{
    const float* enc = (const float*)d_in[0];
    const int* in_len = (const int*)d_in[1];
    const int* tgt_len = (const int*)d_in[2];
    const float* Wd = (const float*)d_in[3];
    const float* bd = (const float*)d_in[4];
    const float* Wp = (const float*)d_in[5];
    const float* bp = (const float*)d_in[6];
    const float* Wo = (const float*)d_in[7];

    char* ws = (char*)d_ws;
    float* g       = (float*)(ws + 0);             // 128 KB
    float* c_a     = (float*)(ws + 131072);        // 128 KB
    float* c_b     = (float*)(ws + 262144);        // 128 KB
    int* fire_t    = (int*)(ws + 393216);          // 32 KB
    int* n_fired   = (int*)(ws + 425984);          // 64 B
    _Float16* WdT0 = (_Float16*)(ws + 458752);     // 2 MB tiled
    _Float16* WdT1 = (_Float16*)(ws + 2555904);    // 2 MB
    _Float16* Wo0  = (_Float16*)(ws + 4653056);    // 1 MB row-major
    _Float16* Wo1  = (_Float16*)(ws + 5701632);    // 1 MB
    _Float16* C0   = (_Float16*)(ws + 6750208);    // 16 MB
    _Float16* C1   = (_Float16*)(ws + 23527424);   // 16 MB  (end ~40.3 MB)

    float* out0 = (float*)d_out;
    float* out_mask = out0 + (size_t)BSZ * TLEN * OUTDIM;
    float* out_dur = out_mask + (size_t)BSZ * TLEN;
    float* out_qty = out_dur + (size_t)BSZ * TLEN;

    (void)hipMemsetAsync(g, 0, 131072, stream);
    (void)hipMemsetAsync(d_out, 0, (size_t)out_size * 4, stream);

    k0a_split_wd<<<dim3(8, 32), 128, 0, stream>>>(Wd, WdT0, WdT1);
    k0c_split_wo<<<512, 256, 0, stream>>>(Wo, Wo0, Wo1);
    k1_weight_gemm<<<2048, 512, 0, stream>>>(enc, WdT0, WdT1, bd, Wp, g);
    k2_scan<<<BSZ, 256, 0, stream>>>(g, in_len, tgt_len, bp, c_a, c_b,
                                     fire_t, n_fired, out_mask, out_dur, out_qty);
    k3a_compact<<<dim3(MAXF, BSZ), 256, 0, stream>>>(enc, c_a, c_b, fire_t,
                                                     n_fired, C0, C1);
    k3b_outproj<<<dim3(8, 4, BSZ), 256, 0, stream>>>(C0, C1, Wo0, Wo1,
                                                     n_fired, out0);
}